// Round 8
// baseline (6015.253 us; speedup 1.0000x reference)
//
#include <hip/hip_runtime.h>
#include <stdint.h>
#include <math.h>

#define BATCH 2
#define SEQ 2048
#define DM 2048
#define NH 16
#define HD 128

typedef unsigned short u16;
typedef __attribute__((ext_vector_type(8))) __bf16 bf16x8;
typedef __attribute__((ext_vector_type(4))) float f32x4;

__device__ inline float bf2f(u16 x) {
    return __uint_as_float(((unsigned)x) << 16);
}
__device__ inline u16 f2bf(float f) {
    unsigned u = __float_as_uint(f);
    return (u16)((u + 0x7FFF + ((u >> 16) & 1)) >> 16);
}
__device__ inline f32x4 mfma16(bf16x8 a, bf16x8 b, f32x4 c) {
    return __builtin_amdgcn_mfma_f32_16x16x32_bf16(a, b, c, 0, 0, 0);
}

// ---------------- transpose 2048x2048, fp32 in -> bf16 out ------------------
__global__ __launch_bounds__(256) void transpose2048(const float* __restrict__ src,
                                                     u16* __restrict__ dst) {
    __shared__ u16 tile[32][33];
    int bx = blockIdx.x * 32, by = blockIdx.y * 32;
    int tx = threadIdx.x & 31, ty = threadIdx.x >> 5;  // ty in 0..7
    #pragma unroll
    for (int i = 0; i < 32; i += 8)
        tile[ty + i][tx] = f2bf(src[(long)(by + ty + i) * DM + bx + tx]);
    __syncthreads();
    #pragma unroll
    for (int i = 0; i < 32; i += 8)
        dst[(long)(bx + ty + i) * DM + by + tx] = tile[tx][ty + i];
}

// ---------------- MFMA GEMM: C(MxN) = A(MxK) * Bt(NxK)^T, fp32 accum --------
// AF32: A fp32 (converted to bf16 during LDS staging) else bf16.
// OUTF32: C stored fp32 (else bf16). Validated: rounds 3/4 bf16 outputs
// matched the semantics-audited VALU GEMM bit-for-bit after bf16 rounding.
#define BM 128
#define BN 128
#define BK 64
#define LPAD 72  // LDS row stride: 64 + 8 pad

template <bool AF32, bool OUTF32>
__global__ __launch_bounds__(256) void gemm_bt(const void* __restrict__ Av,
                                               const u16* __restrict__ Bt,
                                               void* __restrict__ Cv,
                                               int N, int K) {
    __shared__ alignas(16) u16 As[BM * LPAD];
    __shared__ alignas(16) u16 Bs[BN * LPAD];
    int tid = threadIdx.x;
    int wave = tid >> 6, lane = tid & 63;
    int quad = lane >> 4, l16 = lane & 15;
    int wm = wave & 1, wn = wave >> 1;
    long rowBase = (long)blockIdx.y * BM;
    long colBase = (long)blockIdx.x * BN;

    f32x4 acc[4][4];
    #pragma unroll
    for (int i = 0; i < 4; i++)
        #pragma unroll
        for (int j = 0; j < 4; j++) acc[i][j] = (f32x4){0.f, 0.f, 0.f, 0.f};

    for (int k0 = 0; k0 < K; k0 += BK) {
        __syncthreads();
        #pragma unroll
        for (int i = 0; i < 4; i++) {
            int c = tid + i * 256;
            int r = c >> 3, c8 = (c & 7) << 3;
            if (AF32) {
                const float* A = (const float*)Av;
                const float* src = &A[(rowBase + r) * K + k0 + c8];
                float4 v0 = *(const float4*)src;
                float4 v1 = *(const float4*)(src + 4);
                union { uint4 q; u16 e[8]; } u;
                u.e[0] = f2bf(v0.x); u.e[1] = f2bf(v0.y);
                u.e[2] = f2bf(v0.z); u.e[3] = f2bf(v0.w);
                u.e[4] = f2bf(v1.x); u.e[5] = f2bf(v1.y);
                u.e[6] = f2bf(v1.z); u.e[7] = f2bf(v1.w);
                *(uint4*)&As[r * LPAD + c8] = u.q;
            } else {
                const u16* A = (const u16*)Av;
                *(uint4*)&As[r * LPAD + c8] = *(const uint4*)&A[(rowBase + r) * K + k0 + c8];
            }
            *(uint4*)&Bs[r * LPAD + c8] = *(const uint4*)&Bt[(colBase + r) * K + k0 + c8];
        }
        __syncthreads();
        #pragma unroll
        for (int kk = 0; kk < 2; kk++) {
            bf16x8 af[4], bfr[4];
            #pragma unroll
            for (int i = 0; i < 4; i++)
                af[i] = *(const bf16x8*)&As[(wm * 64 + i * 16 + l16) * LPAD + kk * 32 + quad * 8];
            #pragma unroll
            for (int j = 0; j < 4; j++)
                bfr[j] = *(const bf16x8*)&Bs[(wn * 64 + j * 16 + l16) * LPAD + kk * 32 + quad * 8];
            #pragma unroll
            for (int i = 0; i < 4; i++)
                #pragma unroll
                for (int j = 0; j < 4; j++)
                    acc[i][j] = mfma16(af[i], bfr[j], acc[i][j]);
        }
    }
    #pragma unroll
    for (int i = 0; i < 4; i++) {
        #pragma unroll
        for (int j = 0; j < 4; j++) {
            long col = colBase + wn * 64 + j * 16 + l16;
            #pragma unroll
            for (int r = 0; r < 4; r++) {
                long row = rowBase + wm * 64 + i * 16 + quad * 4 + r;
                if (OUTF32) ((float*)Cv)[row * N + col] = acc[i][j][r];
                else        ((u16*)Cv)[row * N + col] = f2bf(acc[i][j][r]);
            }
        }
    }
}

// ---------------- RoPE (in-place on Q and K), rotate_half style -------------
__global__ __launch_bounds__(256) void rope_kernel(u16* __restrict__ Q,
                                                   u16* __restrict__ Kb,
                                                   const int* __restrict__ pid) {
    int idx = blockIdx.x * blockDim.x + threadIdx.x;  // (m, h, d<64)
    int d = idx & 63;
    int h = (idx >> 6) & (NH - 1);
    int m = idx >> 10;  // 0..B*S-1
    int b = m >> 11, s = m & (SEQ - 1);
    int pos = pid[b * SEQ + s];
    double invf = exp2(-(double)d * 0.20762050593046015);  // log2(10000)/64
    float freq = (float)((double)pos * invf);
    float sn = (float)sin((double)freq);
    float cs = (float)cos((double)freq);
    long base = (long)m * DM + h * HD + d;
    float x1 = bf2f(Q[base]), x2 = bf2f(Q[base + 64]);
    Q[base] = f2bf(x1 * cs - x2 * sn);
    Q[base + 64] = f2bf(x2 * cs + x1 * sn);
    float y1 = bf2f(Kb[base]), y2 = bf2f(Kb[base + 64]);
    Kb[base] = f2bf(y1 * cs - y2 * sn);
    Kb[base + 64] = f2bf(y2 * cs + y1 * sn);
}

// ---------------- VALU flash attention (layout-free, verified path) ---------
__global__ __launch_bounds__(256) void attn_valu(const u16* __restrict__ Q,
                                                 const u16* __restrict__ K,
                                                 const u16* __restrict__ V,
                                                 const int* __restrict__ amask,
                                                 u16* __restrict__ O) {
    int wave = threadIdx.x >> 6, lane = threadIdx.x & 63;
    int q = blockIdx.x * 4 + wave;  // 0..SEQ-1
    int bh = blockIdx.y;
    int b = bh >> 4, h = bh & (NH - 1);
    long base = (long)b * SEQ * DM + (long)h * HD;

    unsigned qw = *(const unsigned*)&Q[base + (long)q * DM + 2 * lane];
    float q0 = bf2f((u16)(qw & 0xFFFF)), q1 = bf2f((u16)(qw >> 16));

    const float scale = 0.08838834764831845f;  // 1/sqrt(128)
    float m = -1e30f, l = 0.f, a0 = 0.f, a1 = 0.f;
    const int* mrow = amask + b * SEQ;

    for (int kv = 0; kv <= q; kv++) {
        unsigned kw = *(const unsigned*)&K[base + (long)kv * DM + 2 * lane];
        float sp = q0 * bf2f((u16)(kw & 0xFFFF)) + q1 * bf2f((u16)(kw >> 16));
        #pragma unroll
        for (int off = 1; off < 64; off <<= 1) sp += __shfl_xor(sp, off, 64);
        float s = sp * scale;
        if (mrow[kv] <= 0) s = -1e30f;
        float mn = fmaxf(m, s);
        float al = expf(m - mn);
        float p = expf(s - mn);
        m = mn;
        l = l * al + p;
        unsigned vw = *(const unsigned*)&V[base + (long)kv * DM + 2 * lane];
        a0 = a0 * al + p * bf2f((u16)(vw & 0xFFFF));
        a1 = a1 * al + p * bf2f((u16)(vw >> 16));
    }
    float inv = 1.0f / l;
    unsigned ow = (unsigned)f2bf(a0 * inv) | ((unsigned)f2bf(a1 * inv) << 16);
    *(unsigned*)&O[base + (long)q * DM + 2 * lane] = ow;
}

extern "C" void kernel_launch(void* const* d_in, const int* in_sizes, int n_in,
                              void* d_out, int out_size, void* d_ws, size_t ws_size,
                              hipStream_t stream) {
    // ALL float tensors are fp32 (round-7 on-device detector confirmed inputs;
    // harness out_dtype branch selects fp32 read since reference returns f32).
    const float* X  = (const float*)d_in[0];
    const int* am   = (const int*)d_in[1];
    const int* pid  = (const int*)d_in[2];
    const float* Wq = (const float*)d_in[3];
    const float* Wk = (const float*)d_in[4];
    const float* Wv = (const float*)d_in[5];
    const float* Wo = (const float*)d_in[6];
    float* out = (float*)d_out;  // fp32 output

    // Workspace, 64 MB:
    //   [ 0- 8) WoT   [ 8-16) WvT   [16-24) WqT   [24-32) WkT
    //   [32-48) Qb (attn output in-place)   [48-64) Kb
    //   Vb overlays [16-32) after WqT/WkT are dead.
    char* ws = (char*)d_ws;
    const size_t MB = 1024 * 1024;
    u16* WoT = (u16*)(ws + 0 * MB);
    u16* WvT = (u16*)(ws + 8 * MB);
    u16* WqT = (u16*)(ws + 16 * MB);
    u16* WkT = (u16*)(ws + 24 * MB);
    u16* Qb  = (u16*)(ws + 32 * MB);
    u16* Kb  = (u16*)(ws + 48 * MB);
    u16* Vb  = (u16*)(ws + 16 * MB);  // overlays WqT+WkT

    dim3 tb(256);
    dim3 tg(64, 64);
    transpose2048<<<tg, tb, 0, stream>>>(Wq, WqT);
    transpose2048<<<tg, tb, 0, stream>>>(Wk, WkT);
    transpose2048<<<tg, tb, 0, stream>>>(Wv, WvT);
    transpose2048<<<tg, tb, 0, stream>>>(Wo, WoT);

    dim3 gg(DM / BN, (BATCH * SEQ) / BM);  // (16, 32)
    gemm_bt<true, false><<<gg, tb, 0, stream>>>(X, WqT, Qb, DM, DM);
    gemm_bt<true, false><<<gg, tb, 0, stream>>>(X, WkT, Kb, DM, DM);
    gemm_bt<true, false><<<gg, tb, 0, stream>>>(X, WvT, Vb, DM, DM);  // WqT/WkT dead

    int nrope = BATCH * SEQ * NH * 64;
    rope_kernel<<<nrope / 256, tb, 0, stream>>>(Qb, Kb, pid);

    dim3 ag(SEQ / 4, BATCH * NH);
    attn_valu<<<ag, tb, 0, stream>>>(Qb, Kb, Vb, am, Qb);  // in-place

    gemm_bt<false, true><<<gg, tb, 0, stream>>>(Qb, WoT, out, DM, DM);
}